// Round 3
// baseline (185.902 us; speedup 1.0000x reference)
//
#include <hip/hip_runtime.h>

#define LDSP 136  // padded row stride (272B rows, 16B-aligned for b128)

typedef _Float16 h8 __attribute__((ext_vector_type(8)));
typedef _Float16 h4 __attribute__((ext_vector_type(4)));
typedef float    f4 __attribute__((ext_vector_type(4)));
typedef float    fx16 __attribute__((ext_vector_type(16)));

// ---- fused prep: Mt[f][e] = sum_d Wk[d][f]*Wq[d][e] (f16), ck[f] = sum_d bq[d]*Wk[d][f] ----
// softmax(QK^T) == softmax(X Mt^T X^T + 1 * (ck . X^T)) -- row-constant terms drop.
__global__ void prep(const float* __restrict__ Wq, const float* __restrict__ Wk,
                     const float* __restrict__ bq, _Float16* __restrict__ Mt,
                     float* __restrict__ ck) {
    int idx = blockIdx.x * 256 + threadIdx.x;  // 16384 entries
    int e = idx & 127, f = idx >> 7;
    float a0 = 0.f, a1 = 0.f, a2 = 0.f, a3 = 0.f;
    for (int d = 0; d < 128; d += 4) {
        a0 += Wk[(d + 0) * 128 + f] * Wq[(d + 0) * 128 + e];
        a1 += Wk[(d + 1) * 128 + f] * Wq[(d + 1) * 128 + e];
        a2 += Wk[(d + 2) * 128 + f] * Wq[(d + 2) * 128 + e];
        a3 += Wk[(d + 3) * 128 + f] * Wq[(d + 3) * 128 + e];
    }
    Mt[idx] = (_Float16)((a0 + a1) + (a2 + a3));

    if (blockIdx.x == 0 && threadIdx.x < 128) {
        int t = threadIdx.x;
        float c0 = 0.f, c1 = 0.f, c2 = 0.f, c3 = 0.f;
        for (int d = 0; d < 128; d += 4) {
            c0 += bq[d + 0] * Wk[(d + 0) * 128 + t];
            c1 += bq[d + 1] * Wk[(d + 1) * 128 + t];
            c2 += bq[d + 2] * Wk[(d + 2) * 128 + t];
            c3 += bq[d + 3] * Wk[(d + 3) * 128 + t];
        }
        ck[t] = (c0 + c1) + (c2 + c3);
    }
}

// One block per 128x128 window; 1024 blocks, 2 resident per CU (LDS = 71.7 KB)
// so one block's HBM phase overlaps the other's compute phase.
// Wave v owns row-half hv=v&1 (u/w rows) and tile t4=v>>1 (f/d/w tiles).
// X fragments are loaded DIRECTLY from global f32 into registers (no Xs LDS
// buffer, no stage phase, no B1 barrier) and reused across phases 1 and 2.
__global__ __launch_bounds__(512, 4) void attn(
    const float* __restrict__ x, const _Float16* __restrict__ Mt,
    const float* __restrict__ Wv, const float* __restrict__ ck,
    const float* __restrict__ bv, float* __restrict__ out) {
    __shared__ _Float16 Ts[128 * LDSP];  // T'[w][f]; overwritten with P[w][u] after phase 2
    __shared__ _Float16 Vs[128 * LDSP];  // V transposed: Vs[d][u]
    __shared__ float2   Sm[256];         // softmax (max, sum) exchange, [uhalf][w]

    const int tid  = threadIdx.x;
    const int wv   = tid >> 6;
    const int lane = tid & 63;
    const int l32  = lane & 31;
    const int hi   = lane >> 5;
    const int hv   = wv & 1;   // row-half this wave owns (u and w rows, d-half in phase 3)
    const int t4   = wv >> 1;  // f-tile (Mt rows), d-tile (Wv rows), w-tile (S/P/O rows)

    const size_t base = (size_t)blockIdx.x * (128 * 128);

    // ---- X fragments: rows [hv*64,+32) and [hv*64+32,+32), cols e0*16+hi*8..+8 ----
    // (issued first so the HBM loads are in flight under the weight loads/converts)
    h8 xf0[8], xf1[8];
    {
        const float* xr0 = x + base + (size_t)(hv * 64 + l32) * 128 + hi * 8;
        const float* xr1 = xr0 + 32 * 128;
#pragma unroll
        for (int e0 = 0; e0 < 8; ++e0) {
            f4 a0 = *(const f4*)(xr0 + e0 * 16);
            f4 a1 = *(const f4*)(xr0 + e0 * 16 + 4);
            f4 b0 = *(const f4*)(xr1 + e0 * 16);
            f4 b1 = *(const f4*)(xr1 + e0 * 16 + 4);
            xf0[e0] = (h8){(_Float16)a0.x, (_Float16)a0.y, (_Float16)a0.z, (_Float16)a0.w,
                           (_Float16)a1.x, (_Float16)a1.y, (_Float16)a1.z, (_Float16)a1.w};
            xf1[e0] = (h8){(_Float16)b0.x, (_Float16)b0.y, (_Float16)b0.z, (_Float16)b0.w,
                           (_Float16)b1.x, (_Float16)b1.y, (_Float16)b1.z, (_Float16)b1.w};
        }
    }

    // persistent weight fragments: A = Mt rows [t4*32,+32), B = Wv rows [t4*32,+32)
    h8 mtf[8], wvf[8];
#pragma unroll
    for (int e0 = 0; e0 < 8; ++e0) {
        mtf[e0] = *(const h8*)(Mt + (t4 * 32 + l32) * 128 + e0 * 16 + hi * 8);
        const float* wp = Wv + (t4 * 32 + l32) * 128 + e0 * 16 + hi * 8;
        f4 w0 = *(const f4*)wp;
        f4 w1 = *(const f4*)(wp + 4);
        wvf[e0] = (h8){(_Float16)w0.x, (_Float16)w0.y, (_Float16)w0.z, (_Float16)w0.w,
                       (_Float16)w1.x, (_Float16)w1.y, (_Float16)w1.z, (_Float16)w1.w};
    }
    const float bvv = bv[t4 * 32 + l32];

    // ---- phase 1a: T'[w][f] = sum_e X[w][e] Mt[f][e] + ck[f], w in own half ----
    fx16 accT0, accT1;
    {
        f4 ckv[4];
#pragma unroll
        for (int run = 0; run < 4; ++run)
            ckv[run] = *(const f4*)(ck + t4 * 32 + run * 8 + 4 * hi);
#pragma unroll
        for (int r = 0; r < 16; ++r) accT0[r] = ckv[r >> 2][r & 3];
        accT1 = accT0;
    }
#pragma unroll
    for (int e0 = 0; e0 < 8; ++e0) {
        accT0 = __builtin_amdgcn_mfma_f32_32x32x16_f16(mtf[e0], xf0[e0], accT0, 0, 0, 0);
        accT1 = __builtin_amdgcn_mfma_f32_32x32x16_f16(mtf[e0], xf1[e0], accT1, 0, 0, 0);
    }
    // D: col = w-local = l32, row = f = t4*32 + (r&3)+8*(r>>2)+4*hi  ->  Ts[w][f]
#pragma unroll
    for (int run = 0; run < 4; ++run) {
        h4 h0 = {(_Float16)accT0[run * 4 + 0], (_Float16)accT0[run * 4 + 1],
                 (_Float16)accT0[run * 4 + 2], (_Float16)accT0[run * 4 + 3]};
        *(h4*)(&Ts[(hv * 64 + l32) * LDSP + t4 * 32 + run * 8 + 4 * hi]) = h0;
        h4 h1 = {(_Float16)accT1[run * 4 + 0], (_Float16)accT1[run * 4 + 1],
                 (_Float16)accT1[run * 4 + 2], (_Float16)accT1[run * 4 + 3]};
        *(h4*)(&Ts[(hv * 64 + 32 + l32) * LDSP + t4 * 32 + run * 8 + 4 * hi]) = h1;
    }

    // ---- phase 1b: V[u][d] = sum_e X[u][e] Wv[d][e] + bv[d], u in own half ----
    fx16 accV0, accV1;
#pragma unroll
    for (int r = 0; r < 16; ++r) accV0[r] = bvv;
    accV1 = accV0;
#pragma unroll
    for (int e0 = 0; e0 < 8; ++e0) {
        accV0 = __builtin_amdgcn_mfma_f32_32x32x16_f16(xf0[e0], wvf[e0], accV0, 0, 0, 0);
        accV1 = __builtin_amdgcn_mfma_f32_32x32x16_f16(xf1[e0], wvf[e0], accV1, 0, 0, 0);
    }
    // D: col = d = t4*32 + l32, row = u -> Vs[d][u] (transposed)
#pragma unroll
    for (int run = 0; run < 4; ++run) {
        h4 g0 = {(_Float16)accV0[run * 4 + 0], (_Float16)accV0[run * 4 + 1],
                 (_Float16)accV0[run * 4 + 2], (_Float16)accV0[run * 4 + 3]};
        *(h4*)(&Vs[(t4 * 32 + l32) * LDSP + hv * 64 + run * 8 + 4 * hi]) = g0;
        h4 g1 = {(_Float16)accV1[run * 4 + 0], (_Float16)accV1[run * 4 + 1],
                 (_Float16)accV1[run * 4 + 2], (_Float16)accV1[run * 4 + 3]};
        *(h4*)(&Vs[(t4 * 32 + l32) * LDSP + hv * 64 + 32 + run * 8 + 4 * hi]) = g1;
    }
    __syncthreads();  // B2: Ts, Vs ready

    // ---- phase 2: S[w][u] = sum_f X[u][f] T'[w][f]; w-tile = t4, u-half = hv ----
    // A = xf (registers, no LDS), B = T' rows [t4*32,+32)
    fx16 s0, s1;
#pragma unroll
    for (int r = 0; r < 16; ++r) s0[r] = 0.f;
    s1 = s0;
#pragma unroll
    for (int f0 = 0; f0 < 8; ++f0) {
        h8 tf = *(const h8*)(&Ts[(t4 * 32 + l32) * LDSP + f0 * 16 + hi * 8]);
        s0 = __builtin_amdgcn_mfma_f32_32x32x16_f16(xf0[f0], tf, s0, 0, 0, 0);
        s1 = __builtin_amdgcn_mfma_f32_32x32x16_f16(xf1[f0], tf, s1, 0, 0, 0);
    }
    // softmax over u for col w = t4*32+l32; this wave holds u-half hv (64 vals
    // across 2 hi-lanes x 32 regs). Local-max exp (values <= 1), then one
    // (m,s) exchange with partner wave v^1; rescale folds into normalize.
    float m = -1e30f;
#pragma unroll
    for (int r = 0; r < 16; ++r) m = fmaxf(m, fmaxf(s0[r], s1[r]));
    m = fmaxf(m, __shfl_xor(m, 32, 64));
    float ss = 0.f;
#pragma unroll
    for (int r = 0; r < 16; ++r) {
        s0[r] = __expf(s0[r] - m);
        s1[r] = __expf(s1[r] - m);
        ss += s0[r] + s1[r];
    }
    ss += __shfl_xor(ss, 32, 64);
    if (hi == 0) Sm[hv * 128 + t4 * 32 + l32] = make_float2(m, ss);
    __syncthreads();  // B3: partner's (m,s) ready; also: all T' reads done
    float2 om = Sm[(hv ^ 1) * 128 + t4 * 32 + l32];
    float M   = fmaxf(m, om.x);
    float inv = __expf(m - M) / (ss * __expf(m - M) + om.y * __expf(om.x - M));
    // P[w][u] (f16) into Ts rows [t4*32,+32), cols u in own half
#pragma unroll
    for (int run = 0; run < 4; ++run) {
        h4 p0 = {(_Float16)(s0[run * 4 + 0] * inv), (_Float16)(s0[run * 4 + 1] * inv),
                 (_Float16)(s0[run * 4 + 2] * inv), (_Float16)(s0[run * 4 + 3] * inv)};
        *(h4*)(&Ts[(t4 * 32 + l32) * LDSP + hv * 64 + run * 8 + 4 * hi]) = p0;
        h4 p1 = {(_Float16)(s1[run * 4 + 0] * inv), (_Float16)(s1[run * 4 + 1] * inv),
                 (_Float16)(s1[run * 4 + 2] * inv), (_Float16)(s1[run * 4 + 3] * inv)};
        *(h4*)(&Ts[(t4 * 32 + l32) * LDSP + hv * 64 + 32 + run * 8 + 4 * hi]) = p1;
    }
    __syncthreads();  // B4: P complete (both halves of each w-tile)

    // ---- phase 3: O[w][d] = sum_u P[w][u] V[u][d]; w-tile = t4, d-half = hv ----
    fx16 o0, o1;
#pragma unroll
    for (int r = 0; r < 16; ++r) o0[r] = 0.f;
    o1 = o0;
#pragma unroll
    for (int u0 = 0; u0 < 8; ++u0) {
        h8 pr = *(const h8*)(&Ts[(t4 * 32 + l32) * LDSP + u0 * 16 + hi * 8]);
        h8 v0 = *(const h8*)(&Vs[(hv * 64 + l32) * LDSP + u0 * 16 + hi * 8]);
        h8 v1 = *(const h8*)(&Vs[(hv * 64 + 32 + l32) * LDSP + u0 * 16 + hi * 8]);
        o0 = __builtin_amdgcn_mfma_f32_32x32x16_f16(pr, v0, o0, 0, 0, 0);
        o1 = __builtin_amdgcn_mfma_f32_32x32x16_f16(pr, v1, o1, 0, 0, 0);
    }
    // D: col = d, row = w = t4*32 + (r&3)+8*(r>>2)+4*hi; 128B runs over l32
    float* ob = out + base;
#pragma unroll
    for (int r = 0; r < 16; ++r) {
        int w = t4 * 32 + (r & 3) + 8 * (r >> 2) + 4 * hi;
        ob[(size_t)w * 128 + hv * 64 + l32]      = o0[r];
        ob[(size_t)w * 128 + hv * 64 + 32 + l32] = o1[r];
    }
}

extern "C" void kernel_launch(void* const* d_in, const int* in_sizes, int n_in,
                              void* d_out, int out_size, void* d_ws, size_t ws_size,
                              hipStream_t stream) {
    const float* x  = (const float*)d_in[0];
    const float* Wq = (const float*)d_in[1];
    const float* bq = (const float*)d_in[2];
    const float* Wk = (const float*)d_in[3];
    // bk (d_in[4]) drops out of softmax entirely
    const float* Wv = (const float*)d_in[5];
    const float* bv = (const float*)d_in[6];

    _Float16* Mt  = (_Float16*)d_ws;        // 32 KiB
    float*    ckp = (float*)(Mt + 16384);   // 512 B

    prep<<<64, 256, 0, stream>>>(Wq, Wk, bq, Mt, ckp);
    attn<<<1024, 512, 0, stream>>>(x, Mt, Wv, ckp, bv, (float*)d_out);
}

// Round 4
// 146.930 us; speedup vs baseline: 1.2652x; 1.2652x over previous
//
#include <hip/hip_runtime.h>

#define LDSP 136  // padded row stride (272B rows, 16B-aligned for b128)

typedef _Float16 h8 __attribute__((ext_vector_type(8)));
typedef _Float16 h4 __attribute__((ext_vector_type(4)));
typedef float    f4 __attribute__((ext_vector_type(4)));
typedef float    fx16 __attribute__((ext_vector_type(16)));

// Raw barrier: orders LDS producer->consumer (lgkmcnt) WITHOUT draining vmcnt,
// so prefetch loads and output stores stay in flight across window phases.
// (__syncthreads lowers to s_waitcnt vmcnt(0) lgkmcnt(0) + s_barrier -- that
// vmcnt(0) drain serialized loads/stores/compute once per window: ~10us/window.)
__device__ __forceinline__ void bar_lds() {
    asm volatile("s_waitcnt lgkmcnt(0)" ::: "memory");
    __builtin_amdgcn_s_barrier();
    __builtin_amdgcn_sched_barrier(0);  // rule #18: no hoisting LDS reads above
}

// ---- fused prep: Mt[f][e] = sum_d Wk[d][f]*Wq[d][e] (f16), ck[f] = sum_d bq[d]*Wk[d][f] ----
// softmax(QK^T) == softmax(X Mt^T X^T + 1 * (ck . X^T)) -- row-constant terms drop.
__global__ void prep(const float* __restrict__ Wq, const float* __restrict__ Wk,
                     const float* __restrict__ bq, _Float16* __restrict__ Mt,
                     float* __restrict__ ck) {
    int idx = blockIdx.x * 256 + threadIdx.x;  // 16384 entries
    int e = idx & 127, f = idx >> 7;
    float a0 = 0.f, a1 = 0.f, a2 = 0.f, a3 = 0.f;
    for (int d = 0; d < 128; d += 4) {
        a0 += Wk[(d + 0) * 128 + f] * Wq[(d + 0) * 128 + e];
        a1 += Wk[(d + 1) * 128 + f] * Wq[(d + 1) * 128 + e];
        a2 += Wk[(d + 2) * 128 + f] * Wq[(d + 2) * 128 + e];
        a3 += Wk[(d + 3) * 128 + f] * Wq[(d + 3) * 128 + e];
    }
    Mt[idx] = (_Float16)((a0 + a1) + (a2 + a3));

    if (blockIdx.x == 0 && threadIdx.x < 128) {
        int t = threadIdx.x;
        float c0 = 0.f, c1 = 0.f, c2 = 0.f, c3 = 0.f;
        for (int d = 0; d < 128; d += 4) {
            c0 += bq[d + 0] * Wk[(d + 0) * 128 + t];
            c1 += bq[d + 1] * Wk[(d + 1) * 128 + t];
            c2 += bq[d + 2] * Wk[(d + 2) * 128 + t];
            c3 += bq[d + 3] * Wk[(d + 3) * 128 + t];
        }
        ck[t] = (c0 + c1) + (c2 + c3);
    }
}

// 32x32x16 MFMA, persistent block per CU (4 windows), counted barriers.
// Wave v owns row-half hv=v&1 (u/w rows) and tile-quarter t4=v>>1 (f/d/w tiles).
// X fragments for the wave's 64-row half are loaded ONCE per window in phase 1
// and reused (registers) as phase 2's A operand -- no X re-read from LDS.
__global__ __launch_bounds__(512, 2) void attn(
    const float* __restrict__ x, const _Float16* __restrict__ Mt,
    const float* __restrict__ Wv, const float* __restrict__ ck,
    const float* __restrict__ bv, float* __restrict__ out) {
    __shared__ _Float16 Xs[128 * LDSP];  // X (f16), single buffer (frags persist in regs)
    __shared__ _Float16 Ts[128 * LDSP];  // T'[w][f]; overwritten with P[w][u] after phase 2
    __shared__ _Float16 Vs[128 * LDSP];  // V transposed: Vs[d][u]
    __shared__ float2   Sm[256];         // softmax (max, sum) exchange, [uhalf][w]

    const int tid  = threadIdx.x;
    const int wv   = tid >> 6;
    const int lane = tid & 63;
    const int l32  = lane & 31;
    const int hi   = lane >> 5;
    const int hv   = wv & 1;   // row-half this wave owns (u and w rows, d-half in phase 3)
    const int t4   = wv >> 1;  // f-tile (Mt rows), d-tile (Wv rows), w-tile (S/P/O rows)

    // persistent weight fragments: A = Mt rows [t4*32,+32), B = Wv rows [t4*32,+32)
    h8 mtf[8], wvf[8];
#pragma unroll
    for (int e0 = 0; e0 < 8; ++e0) {
        mtf[e0] = *(const h8*)(Mt + (t4 * 32 + l32) * 128 + e0 * 16 + hi * 8);
        const float* wp = Wv + (t4 * 32 + l32) * 128 + e0 * 16 + hi * 8;
        f4 w0 = *(const f4*)wp;
        f4 w1 = *(const f4*)(wp + 4);
        wvf[e0] = (h8){(_Float16)w0.x, (_Float16)w0.y, (_Float16)w0.z, (_Float16)w0.w,
                       (_Float16)w1.x, (_Float16)w1.y, (_Float16)w1.z, (_Float16)w1.w};
    }
    const float bvv = bv[t4 * 32 + l32];

    const size_t base0 = (size_t)blockIdx.x * 4 * (128 * 128);

    // prefetch window 0 into registers
    f4 pf[8];
#pragma unroll
    for (int j = 0; j < 8; ++j)
        pf[j] = *(const f4*)(x + base0 + 4 * tid + 2048 * j);

    for (int it = 0; it < 4; ++it) {
        // ---- stage: convert prefetched regs -> Xs (f16) ----
#pragma unroll
        for (int j = 0; j < 8; ++j) {
            int idx = 4 * tid + 2048 * j;
            int row = idx >> 7, col = idx & 127;
            f4 f = pf[j];
            h4 h = {(_Float16)f.x, (_Float16)f.y, (_Float16)f.z, (_Float16)f.w};
            *(h4*)(&Xs[row * LDSP + col]) = h;
        }
        // ---- issue prefetch for next window (pf regs dead after stage-convert;
        //      loads stay in flight across all barriers below) ----
        if (it < 3) {
            const float* nx = x + base0 + (size_t)(it + 1) * (128 * 128);
#pragma unroll
            for (int j = 0; j < 8; ++j)
                pf[j] = *(const f4*)(nx + 4 * tid + 2048 * j);
        }
        bar_lds();  // B1: Xs ready (also fences prev window's Ts/Vs/Xs readers)

        // ---- phase 1a: T'[w][f] = sum_e X[w][e] Mt[f][e] + ck[f], w in own half ----
        h8 xf0[8], xf1[8];  // X rows [hv*64,+32) / [hv*64+32,+32) -- kept for phase 2
        fx16 accT0, accT1;
        {
            f4 ckv[4];
#pragma unroll
            for (int run = 0; run < 4; ++run)
                ckv[run] = *(const f4*)(ck + t4 * 32 + run * 8 + 4 * hi);
#pragma unroll
            for (int r = 0; r < 16; ++r) accT0[r] = ckv[r >> 2][r & 3];
            accT1 = accT0;
        }
#pragma unroll
        for (int e0 = 0; e0 < 8; ++e0) {
            xf0[e0] = *(const h8*)(&Xs[(hv * 64 + l32) * LDSP + e0 * 16 + hi * 8]);
            xf1[e0] = *(const h8*)(&Xs[(hv * 64 + 32 + l32) * LDSP + e0 * 16 + hi * 8]);
            accT0 = __builtin_amdgcn_mfma_f32_32x32x16_f16(mtf[e0], xf0[e0], accT0, 0, 0, 0);
            accT1 = __builtin_amdgcn_mfma_f32_32x32x16_f16(mtf[e0], xf1[e0], accT1, 0, 0, 0);
        }
        // D: col = w-local = l32, row = f = t4*32 + (r&3)+8*(r>>2)+4*hi  ->  Ts[w][f]
#pragma unroll
        for (int run = 0; run < 4; ++run) {
            h4 h0 = {(_Float16)accT0[run * 4 + 0], (_Float16)accT0[run * 4 + 1],
                     (_Float16)accT0[run * 4 + 2], (_Float16)accT0[run * 4 + 3]};
            *(h4*)(&Ts[(hv * 64 + l32) * LDSP + t4 * 32 + run * 8 + 4 * hi]) = h0;
            h4 h1 = {(_Float16)accT1[run * 4 + 0], (_Float16)accT1[run * 4 + 1],
                     (_Float16)accT1[run * 4 + 2], (_Float16)accT1[run * 4 + 3]};
            *(h4*)(&Ts[(hv * 64 + 32 + l32) * LDSP + t4 * 32 + run * 8 + 4 * hi]) = h1;
        }

        // ---- phase 1b: V[u][d] = sum_e X[u][e] Wv[d][e] + bv[d], u in own half ----
        fx16 accV0, accV1;
#pragma unroll
        for (int r = 0; r < 16; ++r) accV0[r] = bvv;
        accV1 = accV0;
#pragma unroll
        for (int e0 = 0; e0 < 8; ++e0) {
            accV0 = __builtin_amdgcn_mfma_f32_32x32x16_f16(xf0[e0], wvf[e0], accV0, 0, 0, 0);
            accV1 = __builtin_amdgcn_mfma_f32_32x32x16_f16(xf1[e0], wvf[e0], accV1, 0, 0, 0);
        }
        // D: col = d = t4*32 + l32, row = u -> Vs[d][u] (transposed)
#pragma unroll
        for (int run = 0; run < 4; ++run) {
            h4 g0 = {(_Float16)accV0[run * 4 + 0], (_Float16)accV0[run * 4 + 1],
                     (_Float16)accV0[run * 4 + 2], (_Float16)accV0[run * 4 + 3]};
            *(h4*)(&Vs[(t4 * 32 + l32) * LDSP + hv * 64 + run * 8 + 4 * hi]) = g0;
            h4 g1 = {(_Float16)accV1[run * 4 + 0], (_Float16)accV1[run * 4 + 1],
                     (_Float16)accV1[run * 4 + 2], (_Float16)accV1[run * 4 + 3]};
            *(h4*)(&Vs[(t4 * 32 + l32) * LDSP + hv * 64 + 32 + run * 8 + 4 * hi]) = g1;
        }
        bar_lds();  // B2: Ts, Vs ready

        // ---- phase 2: S[w][u] = sum_f X[u][f] T'[w][f]; w-tile = t4, u-half = hv ----
        // A = xf (registers, no LDS), B = T' rows [t4*32,+32)
        fx16 s0, s1;
#pragma unroll
        for (int r = 0; r < 16; ++r) s0[r] = 0.f;
        s1 = s0;
#pragma unroll
        for (int f0 = 0; f0 < 8; ++f0) {
            h8 tf = *(const h8*)(&Ts[(t4 * 32 + l32) * LDSP + f0 * 16 + hi * 8]);
            s0 = __builtin_amdgcn_mfma_f32_32x32x16_f16(xf0[f0], tf, s0, 0, 0, 0);
            s1 = __builtin_amdgcn_mfma_f32_32x32x16_f16(xf1[f0], tf, s1, 0, 0, 0);
        }
        // softmax over u for col w = t4*32+l32; this wave holds u-half hv (64 vals
        // across 2 hi-lanes x 32 regs). Local-max exp (values <= 1), then one
        // (m,s) exchange with partner wave v^1; rescale folds into normalize.
        float m = -1e30f;
#pragma unroll
        for (int r = 0; r < 16; ++r) m = fmaxf(m, fmaxf(s0[r], s1[r]));
        m = fmaxf(m, __shfl_xor(m, 32, 64));
        float ss = 0.f;
#pragma unroll
        for (int r = 0; r < 16; ++r) {
            s0[r] = __expf(s0[r] - m);
            s1[r] = __expf(s1[r] - m);
            ss += s0[r] + s1[r];
        }
        ss += __shfl_xor(ss, 32, 64);
        if (hi == 0) Sm[hv * 128 + t4 * 32 + l32] = make_float2(m, ss);
        bar_lds();  // B3: partner's (m,s) ready; all phase-2 T' reads already consumed
        float2 om = Sm[(hv ^ 1) * 128 + t4 * 32 + l32];
        float M   = fmaxf(m, om.x);
        float inv = __expf(m - M) / (ss * __expf(m - M) + om.y * __expf(om.x - M));
        // P[w][u] (f16) into Ts rows [t4*32,+32), cols u in own half
#pragma unroll
        for (int run = 0; run < 4; ++run) {
            h4 p0 = {(_Float16)(s0[run * 4 + 0] * inv), (_Float16)(s0[run * 4 + 1] * inv),
                     (_Float16)(s0[run * 4 + 2] * inv), (_Float16)(s0[run * 4 + 3] * inv)};
            *(h4*)(&Ts[(t4 * 32 + l32) * LDSP + hv * 64 + run * 8 + 4 * hi]) = p0;
            h4 p1 = {(_Float16)(s1[run * 4 + 0] * inv), (_Float16)(s1[run * 4 + 1] * inv),
                     (_Float16)(s1[run * 4 + 2] * inv), (_Float16)(s1[run * 4 + 3] * inv)};
            *(h4*)(&Ts[(t4 * 32 + l32) * LDSP + hv * 64 + 32 + run * 8 + 4 * hi]) = p1;
        }
        bar_lds();  // B4: P complete (both halves of each w-tile)

        // ---- phase 3: O[w][d] = sum_u P[w][u] V[u][d]; w-tile = t4, d-half = hv ----
        fx16 o0, o1;
#pragma unroll
        for (int r = 0; r < 16; ++r) o0[r] = 0.f;
        o1 = o0;
#pragma unroll
        for (int u0 = 0; u0 < 8; ++u0) {
            h8 pr = *(const h8*)(&Ts[(t4 * 32 + l32) * LDSP + u0 * 16 + hi * 8]);
            h8 v0 = *(const h8*)(&Vs[(hv * 64 + l32) * LDSP + u0 * 16 + hi * 8]);
            h8 v1 = *(const h8*)(&Vs[(hv * 64 + 32 + l32) * LDSP + u0 * 16 + hi * 8]);
            o0 = __builtin_amdgcn_mfma_f32_32x32x16_f16(pr, v0, o0, 0, 0, 0);
            o1 = __builtin_amdgcn_mfma_f32_32x32x16_f16(pr, v1, o1, 0, 0, 0);
        }
        // D: col = d, row = w = t4*32 + (r&3)+8*(r>>2)+4*hi; 128B runs over l32.
        // Stores are never vmcnt-waited inside the loop -> drain under next window.
        float* ob = out + base0 + (size_t)it * (128 * 128);
#pragma unroll
        for (int r = 0; r < 16; ++r) {
            int w = t4 * 32 + (r & 3) + 8 * (r >> 2) + 4 * hi;
            ob[(size_t)w * 128 + hv * 64 + l32]      = o0[r];
            ob[(size_t)w * 128 + hv * 64 + 32 + l32] = o1[r];
        }
    }
}

extern "C" void kernel_launch(void* const* d_in, const int* in_sizes, int n_in,
                              void* d_out, int out_size, void* d_ws, size_t ws_size,
                              hipStream_t stream) {
    const float* x  = (const float*)d_in[0];
    const float* Wq = (const float*)d_in[1];
    const float* bq = (const float*)d_in[2];
    const float* Wk = (const float*)d_in[3];
    // bk (d_in[4]) drops out of softmax entirely
    const float* Wv = (const float*)d_in[5];
    const float* bv = (const float*)d_in[6];

    _Float16* Mt  = (_Float16*)d_ws;        // 32 KiB
    float*    ckp = (float*)(Mt + 16384);   // 512 B

    prep<<<64, 256, 0, stream>>>(Wq, Wk, bq, Mt, ckp);
    attn<<<256, 512, 0, stream>>>(x, Mt, Wv, ckp, bv, (float*)d_out);
}

// Round 5
// 146.533 us; speedup vs baseline: 1.2687x; 1.0027x over previous
//
#include <hip/hip_runtime.h>

#define LDSP 136  // padded row stride (272B rows, 16B-aligned for b128)

typedef _Float16 h8 __attribute__((ext_vector_type(8)));
typedef _Float16 h4 __attribute__((ext_vector_type(4)));
typedef float    f4 __attribute__((ext_vector_type(4)));
typedef float    fx16 __attribute__((ext_vector_type(16)));
typedef unsigned u32x4 __attribute__((ext_vector_type(4)));

union VF { u32x4 u; h8 h; };

// lgkm-only barrier (no vmcnt drain); sched_barrier stops read hoisting (rule #18)
__device__ __forceinline__ void bar_lds() {
    asm volatile("s_waitcnt lgkmcnt(0)" ::: "memory");
    __builtin_amdgcn_s_barrier();
    __builtin_amdgcn_sched_barrier(0);
}

// pack two f32 -> one u32 of two f16 (RNE via scalar casts, matches reference rounding)
__device__ __forceinline__ unsigned pkh(float a, float b) {
    union { _Float16 h[2]; unsigned u; } t;
    t.h[0] = (_Float16)a; t.h[1] = (_Float16)b;
    return t.u;
}

// ---- fused prep: Mt[f][e] = sum_d Wk[d][f]*Wq[d][e] (f16); Wvh = f16(Wv);
//      ck[f] = sum_d bq[d]*Wk[d][f].  64 blocks x 256. ----
__global__ void prep(const float* __restrict__ Wq, const float* __restrict__ Wk,
                     const float* __restrict__ bq, const float* __restrict__ Wv,
                     _Float16* __restrict__ Mt, _Float16* __restrict__ Wvh,
                     float* __restrict__ ck) {
    int idx = blockIdx.x * 256 + threadIdx.x;  // 16384 entries
    int e = idx & 127, f = idx >> 7;
    float a0 = 0.f, a1 = 0.f, a2 = 0.f, a3 = 0.f;
    for (int d = 0; d < 128; d += 4) {
        a0 += Wk[(d + 0) * 128 + f] * Wq[(d + 0) * 128 + e];
        a1 += Wk[(d + 1) * 128 + f] * Wq[(d + 1) * 128 + e];
        a2 += Wk[(d + 2) * 128 + f] * Wq[(d + 2) * 128 + e];
        a3 += Wk[(d + 3) * 128 + f] * Wq[(d + 3) * 128 + e];
    }
    Mt[idx]  = (_Float16)((a0 + a1) + (a2 + a3));
    Wvh[idx] = (_Float16)Wv[idx];

    if (blockIdx.x == 0 && threadIdx.x < 128) {
        int t = threadIdx.x;
        float c0 = 0.f, c1 = 0.f, c2 = 0.f, c3 = 0.f;
        for (int d = 0; d < 128; d += 4) {
            c0 += bq[d + 0] * Wk[(d + 0) * 128 + t];
            c1 += bq[d + 1] * Wk[(d + 1) * 128 + t];
            c2 += bq[d + 2] * Wk[(d + 2) * 128 + t];
            c3 += bq[d + 3] * Wk[(d + 3) * 128 + t];
        }
        ck[t] = (c0 + c1) + (c2 + c3);
    }
}

// One block per 128x128 window, 1024 blocks, TWO resident blocks per CU
// (LDS 70KB, VGPR<=128) so one block's memory phases overlap the other's
// compute. V never touches LDS: each wave computes V[all u][its 32-d strip]
// (partner-redundant) and converts the MFMA C-layout into phase-3 B-fragments
// in-register via f16 packing + v_permlane32_swap_b32 (hi-half k exchange).
__global__ __launch_bounds__(512, 4) void attn(
    const float* __restrict__ x, const _Float16* __restrict__ Mt,
    const _Float16* __restrict__ Wvh, const float* __restrict__ ck,
    const float* __restrict__ bv, float* __restrict__ out) {
    __shared__ _Float16 Xs[128 * LDSP];  // X (f16); re-read in phases 1 and 2
    __shared__ _Float16 Ts[128 * LDSP];  // T'[w][f]; overwritten with P[w][u]
    __shared__ float2   Sm[256];         // softmax (max,sum) exchange [uhalf][w]

    const int tid  = threadIdx.x;
    const int wv   = tid >> 6;
    const int lane = tid & 63;
    const int l32  = lane & 31;
    const int hi   = lane >> 5;
    const int hv   = wv & 1;   // w/u half (phases 1a,2); w-tile pair (phase 3)
    const int t4   = wv >> 1;  // f-strip (T'), d-strip (V/O), w-tile (S/P)

    const size_t base = (size_t)blockIdx.x * (128 * 128);

    // ---- stage: global f32 -> Xs f16 ----
#pragma unroll
    for (int j = 0; j < 8; ++j) {
        int idx = 4 * tid + 2048 * j;
        int row = idx >> 7, col = idx & 127;
        f4 f = *(const f4*)(x + base + idx);
        h4 h = {(_Float16)f.x, (_Float16)f.y, (_Float16)f.z, (_Float16)f.w};
        *(h4*)(&Xs[row * LDSP + col]) = h;
    }
    bar_lds();  // B1: Xs ready

    const float bvv = bv[t4 * 32 + l32];

    // ---- phase 1b: V[u][d] = sum_e X[u][e] Wvh[d][e] + bv[d], ALL u, d-strip t4.
    //      C-layout: col d = t4*32+l32, row u = ut*32+(r&3)+8(r>>2)+4hi.
    //      Convert to phase-3 B-frags: k=u, col=d; lane needs u = 16s+hi*8+j. ----
    VF vfr[8];
    {
        fx16 av0, av1, av2, av3;
#pragma unroll
        for (int r = 0; r < 16; ++r) av0[r] = bvv;
        av1 = av0; av2 = av0; av3 = av0;
#pragma unroll
        for (int e0 = 0; e0 < 8; ++e0) {
            h8 wf = *(const h8*)(Wvh + (t4 * 32 + l32) * 128 + e0 * 16 + hi * 8);
            h8 x0 = *(const h8*)(&Xs[( 0 + l32) * LDSP + e0 * 16 + hi * 8]);
            h8 x1 = *(const h8*)(&Xs[(32 + l32) * LDSP + e0 * 16 + hi * 8]);
            h8 x2 = *(const h8*)(&Xs[(64 + l32) * LDSP + e0 * 16 + hi * 8]);
            h8 x3 = *(const h8*)(&Xs[(96 + l32) * LDSP + e0 * 16 + hi * 8]);
            av0 = __builtin_amdgcn_mfma_f32_32x32x16_f16(x0, wf, av0, 0, 0, 0);
            av1 = __builtin_amdgcn_mfma_f32_32x32x16_f16(x1, wf, av1, 0, 0, 0);
            av2 = __builtin_amdgcn_mfma_f32_32x32x16_f16(x2, wf, av2, 0, 0, 0);
            av3 = __builtin_amdgcn_mfma_f32_32x32x16_f16(x3, wf, av3, 0, 0, 0);
        }
        // per u-tile: pairs A*={u+0..3,+4hi}, B*={u+8..11,+4hi}, C*={+16..19}, D*={+24..27};
        // permlane32_swap(X,Y): X' = [X.lo|Y.lo], Y' = [X.hi|Y.hi]  ->
        // step 2T frag {A0',A1',B0',B1'} = u 16T*2+{0..7|8..15}, step 2T+1 {C0',C1',D0',D1'}.
#define PACK_TILE(av, T) {                                                        \
        unsigned A0 = pkh(av[0], av[1]),  A1 = pkh(av[2], av[3]);                 \
        unsigned B0 = pkh(av[4], av[5]),  B1 = pkh(av[6], av[7]);                 \
        unsigned C0 = pkh(av[8], av[9]),  C1 = pkh(av[10], av[11]);               \
        unsigned D0 = pkh(av[12], av[13]), D1 = pkh(av[14], av[15]);              \
        asm volatile("v_permlane32_swap_b32 %0, %1" : "+v"(A0), "+v"(B0));        \
        asm volatile("v_permlane32_swap_b32 %0, %1" : "+v"(A1), "+v"(B1));        \
        asm volatile("v_permlane32_swap_b32 %0, %1" : "+v"(C0), "+v"(D0));        \
        asm volatile("v_permlane32_swap_b32 %0, %1" : "+v"(C1), "+v"(D1));        \
        vfr[2 * T].u     = (u32x4){A0, A1, B0, B1};                               \
        vfr[2 * T + 1].u = (u32x4){C0, C1, D0, D1};                               \
    }
        PACK_TILE(av0, 0) PACK_TILE(av1, 1) PACK_TILE(av2, 2) PACK_TILE(av3, 3)
#undef PACK_TILE
    }

    // ---- phase 1a: T'[w][f] = sum_e X[w][e] Mt[f][e] + ck[f]; w in hv-half ----
    {
        fx16 accT0, accT1;
        {
            f4 ckv[4];
#pragma unroll
            for (int run = 0; run < 4; ++run)
                ckv[run] = *(const f4*)(ck + t4 * 32 + run * 8 + 4 * hi);
#pragma unroll
            for (int r = 0; r < 16; ++r) accT0[r] = ckv[r >> 2][r & 3];
            accT1 = accT0;
        }
#pragma unroll
        for (int e0 = 0; e0 < 8; ++e0) {
            h8 mt = *(const h8*)(Mt + (t4 * 32 + l32) * 128 + e0 * 16 + hi * 8);
            h8 b0 = *(const h8*)(&Xs[(hv * 64 + l32) * LDSP + e0 * 16 + hi * 8]);
            h8 b1 = *(const h8*)(&Xs[(hv * 64 + 32 + l32) * LDSP + e0 * 16 + hi * 8]);
            accT0 = __builtin_amdgcn_mfma_f32_32x32x16_f16(mt, b0, accT0, 0, 0, 0);
            accT1 = __builtin_amdgcn_mfma_f32_32x32x16_f16(mt, b1, accT1, 0, 0, 0);
        }
        // D: col = w = l32, row = f = t4*32+(r&3)+8(r>>2)+4hi  ->  Ts[w][f]
#pragma unroll
        for (int run = 0; run < 4; ++run) {
            h4 h0 = {(_Float16)accT0[run * 4 + 0], (_Float16)accT0[run * 4 + 1],
                     (_Float16)accT0[run * 4 + 2], (_Float16)accT0[run * 4 + 3]};
            *(h4*)(&Ts[(hv * 64 + l32) * LDSP + t4 * 32 + run * 8 + 4 * hi]) = h0;
            h4 h1 = {(_Float16)accT1[run * 4 + 0], (_Float16)accT1[run * 4 + 1],
                     (_Float16)accT1[run * 4 + 2], (_Float16)accT1[run * 4 + 3]};
            *(h4*)(&Ts[(hv * 64 + 32 + l32) * LDSP + t4 * 32 + run * 8 + 4 * hi]) = h1;
        }
    }
    bar_lds();  // B2: T' complete

    // ---- phase 2: S[w][u] = sum_f X[u][f] T'[w][f]; w-tile t4, u-half hv ----
    fx16 s0, s1;
#pragma unroll
    for (int r = 0; r < 16; ++r) s0[r] = 0.f;
    s1 = s0;
#pragma unroll
    for (int f0 = 0; f0 < 8; ++f0) {
        h8 tf = *(const h8*)(&Ts[(t4 * 32 + l32) * LDSP + f0 * 16 + hi * 8]);
        h8 a0 = *(const h8*)(&Xs[(hv * 64 + l32) * LDSP + f0 * 16 + hi * 8]);
        h8 a1 = *(const h8*)(&Xs[(hv * 64 + 32 + l32) * LDSP + f0 * 16 + hi * 8]);
        s0 = __builtin_amdgcn_mfma_f32_32x32x16_f16(a0, tf, s0, 0, 0, 0);
        s1 = __builtin_amdgcn_mfma_f32_32x32x16_f16(a1, tf, s1, 0, 0, 0);
    }
    // softmax over u for col w = t4*32+l32 (u-half hv local; halves merged via Sm)
    float m = -1e30f;
#pragma unroll
    for (int r = 0; r < 16; ++r) m = fmaxf(m, fmaxf(s0[r], s1[r]));
    m = fmaxf(m, __shfl_xor(m, 32, 64));
    float ss = 0.f;
#pragma unroll
    for (int r = 0; r < 16; ++r) {
        s0[r] = __expf(s0[r] - m);
        s1[r] = __expf(s1[r] - m);
        ss += s0[r] + s1[r];
    }
    ss += __shfl_xor(ss, 32, 64);
    if (hi == 0) Sm[hv * 128 + t4 * 32 + l32] = make_float2(m, ss);
    bar_lds();  // B3: partner (m,s) ready; all T' reads consumed
    float2 om = Sm[(hv ^ 1) * 128 + t4 * 32 + l32];
    float M   = fmaxf(m, om.x);
    float inv = __expf(m - M) / (ss * __expf(m - M) + om.y * __expf(om.x - M));
    // P[w][u] (f16) into Ts rows [t4*32,+32), u cols in own half
#pragma unroll
    for (int run = 0; run < 4; ++run) {
        h4 p0 = {(_Float16)(s0[run * 4 + 0] * inv), (_Float16)(s0[run * 4 + 1] * inv),
                 (_Float16)(s0[run * 4 + 2] * inv), (_Float16)(s0[run * 4 + 3] * inv)};
        *(h4*)(&Ts[(t4 * 32 + l32) * LDSP + hv * 64 + run * 8 + 4 * hi]) = p0;
        h4 p1 = {(_Float16)(s1[run * 4 + 0] * inv), (_Float16)(s1[run * 4 + 1] * inv),
                 (_Float16)(s1[run * 4 + 2] * inv), (_Float16)(s1[run * 4 + 3] * inv)};
        *(h4*)(&Ts[(t4 * 32 + l32) * LDSP + hv * 64 + 32 + run * 8 + 4 * hi]) = p1;
    }
    bar_lds();  // B4: P complete

    // ---- phase 3: O[w][d] = sum_u P[w][u] V[u][d]; w-tiles {hv, hv+2}, d-strip t4.
    //      A = P from Ts (k = u contiguous), B = vfr (registers) ----
    fx16 o0, o1;
#pragma unroll
    for (int r = 0; r < 16; ++r) o0[r] = 0.f;
    o1 = o0;
#pragma unroll
    for (int us = 0; us < 8; ++us) {
        h8 p0 = *(const h8*)(&Ts[(hv * 32 + l32) * LDSP + us * 16 + hi * 8]);
        h8 p1 = *(const h8*)(&Ts[((2 + hv) * 32 + l32) * LDSP + us * 16 + hi * 8]);
        o0 = __builtin_amdgcn_mfma_f32_32x32x16_f16(p0, vfr[us].h, o0, 0, 0, 0);
        o1 = __builtin_amdgcn_mfma_f32_32x32x16_f16(p1, vfr[us].h, o1, 0, 0, 0);
    }
    // D: col = d = t4*32+l32, row = w = wtile*32+(r&3)+8(r>>2)+4hi
    float* ob = out + base;
#pragma unroll
    for (int r = 0; r < 16; ++r) {
        int wrow = (r & 3) + 8 * (r >> 2) + 4 * hi;
        ob[(size_t)(hv * 32 + wrow) * 128 + t4 * 32 + l32]       = o0[r];
        ob[(size_t)((2 + hv) * 32 + wrow) * 128 + t4 * 32 + l32] = o1[r];
    }
}

extern "C" void kernel_launch(void* const* d_in, const int* in_sizes, int n_in,
                              void* d_out, int out_size, void* d_ws, size_t ws_size,
                              hipStream_t stream) {
    const float* x  = (const float*)d_in[0];
    const float* Wq = (const float*)d_in[1];
    const float* bq = (const float*)d_in[2];
    const float* Wk = (const float*)d_in[3];
    // bk (d_in[4]) drops out of softmax entirely
    const float* Wv = (const float*)d_in[5];
    const float* bv = (const float*)d_in[6];

    _Float16* Mt  = (_Float16*)d_ws;        // 32 KiB
    _Float16* Wvh = Mt + 16384;             // 32 KiB
    float*    ckp = (float*)(Wvh + 16384);  // 512 B

    prep<<<64, 256, 0, stream>>>(Wq, Wk, bq, Wv, Mt, Wvh, ckp);
    attn<<<1024, 512, 0, stream>>>(x, Mt, Wvh, ckp, bv, (float*)d_out);
}